// Round 7
// baseline (154.074 us; speedup 1.0000x reference)
//
#include <hip/hip_runtime.h>
#include <hip/hip_bf16.h>

typedef unsigned short u16;
typedef __attribute__((ext_vector_type(8))) short bf16x8;
typedef __attribute__((ext_vector_type(4))) float f32x4;
typedef __attribute__((ext_vector_type(4))) float float4v;
typedef __attribute__((ext_vector_type(4))) short short4v;
typedef __attribute__((ext_vector_type(4))) int int4v;

#define BB 4
#define SS 2048
#define DD 1024

__device__ __forceinline__ u16 f2bf(float x){
    unsigned u = __float_as_uint(x);
    return (u16)((u + 0x7fffu + ((u >> 16) & 1u)) >> 16);  // RNE
}

#define GLD16(g, l) __builtin_amdgcn_global_load_lds( \
    (const __attribute__((address_space(1))) unsigned int*)(g), \
    (__attribute__((address_space(3))) unsigned int*)(l), 16, 0, 0)

#define SCHED0() __builtin_amdgcn_sched_barrier(0)
#define PH_PRE()  SCHED0(); __builtin_amdgcn_s_barrier(); SCHED0(); __builtin_amdgcn_s_setprio(1)
#define PH_POST() __builtin_amdgcn_s_setprio(0); SCHED0(); __builtin_amdgcn_s_barrier(); SCHED0()

// ---------------- prepass: f32 -> bf16 elementwise (optional scale) ----------------
__global__ void conv_bf16_kernel(const float* __restrict__ in,
                                 u16* __restrict__ out, int n4, float scale){
    int i = blockIdx.x * 256 + threadIdx.x;
    if (i >= n4) return;
    float4v v = ((const float4v*)in)[i];
    short4v o;
    o[0] = (short)f2bf(v[0] * scale); o[1] = (short)f2bf(v[1] * scale);
    o[2] = (short)f2bf(v[2] * scale); o[3] = (short)f2bf(v[3] * scale);
    ((short4v*)out)[i] = o;
}

// ---------------- prepass: V [b][s][d] f32 -> Vt [b][d][s] bf16 ----------------
__global__ void transpose_v_kernel(const float* __restrict__ v,
                                   u16* __restrict__ vt){
    __shared__ float tile[64][65];
    const int b  = blockIdx.z;
    const int s0 = blockIdx.x << 6;
    const int d0 = blockIdx.y << 6;
    const int tx = threadIdx.x & 15;
    const int ty = threadIdx.x >> 4;
#pragma unroll
    for (int kk = 0; kk < 4; ++kk){
        const float* p = v + ((b * SS + s0 + ty + 16 * kk) * DD) + d0 + tx * 4;
        float4v val = *(const float4v*)p;
        tile[ty + 16 * kk][tx * 4 + 0] = val[0];
        tile[ty + 16 * kk][tx * 4 + 1] = val[1];
        tile[ty + 16 * kk][tx * 4 + 2] = val[2];
        tile[ty + 16 * kk][tx * 4 + 3] = val[3];
    }
    __syncthreads();
#pragma unroll
    for (int kk = 0; kk < 4; ++kk){
        int dy = ty + 16 * kk;
        short4v o;
        o[0] = (short)f2bf(tile[tx * 4 + 0][dy]);
        o[1] = (short)f2bf(tile[tx * 4 + 1][dy]);
        o[2] = (short)f2bf(tile[tx * 4 + 2][dy]);
        o[3] = (short)f2bf(tile[tx * 4 + 3][dy]);
        *(short4v*)&vt[((b * DD + d0 + dy) * SS) + s0 + tx * 4] = o;
    }
}

__global__ void zero_f32(float* __restrict__ p, int n){
    int i = blockIdx.x * 256 + threadIdx.x;
    if (i < n) p[i] = 0.f;
}

// ---------------- pass 1: S^T-fragments = K Q^T -> mask/exp -> P bf16, rowsum ----------------
// 512 blocks, 512 threads. 128 q x 256 kv tile, BK=64, 8-phase counted-vmcnt,
// T2 swizzle, T5 setprio. MFMA operands SWAPPED (A=K, B=Q) so each thread's
// C-fragment holds 4 CONSECUTIVE kv for one q-row -> int4 mask load, short4 P store.
__global__ __launch_bounds__(512, 2) void qk_kernel(
    const u16* __restrict__ Qb, const u16* __restrict__ Kb,
    const int* __restrict__ maskg, u16* __restrict__ P,
    float* __restrict__ rowsum)
{
    __shared__ __align__(16) u16 Qs[2][128 * 64];   // 32 KB (q rows x k)
    __shared__ __align__(16) u16 Ks[2][256 * 64];   // 64 KB (kv rows x k)

    const int swz = ((blockIdx.x & 7) << 6) + (blockIdx.x >> 3);  // 512 blocks, bijective
    const int b   = swz >> 7;
    const int bx  = (swz >> 3) & 15;    // 16 q-row tiles of 128
    const int by  = swz & 7;            // 8 kv-col tiles of 256
    const int row0 = bx << 7, col0 = by << 8;

    const int tid = threadIdx.x;
    const int wid = tid >> 6, lane = tid & 63;
    const int l16 = lane & 15, g4 = lane >> 4;
    const int wq = wid >> 2, wk = wid & 3;   // wave covers q[wq*64,+64) x kv[wk*64,+64)

    const int sr   = tid >> 3;
    const int scol = ((tid & 7) ^ (sr & 7)) << 3;
    const u16* gA = Qb + (size_t)(b * SS + row0 + sr) * DD + scol;
    const u16* gB = Kb + (size_t)(b * SS + col0 + sr) * DD + scol;
    char* const lA0 = (char*)Qs[0] + tid * 16;
    char* const lB0 = (char*)Ks[0] + tid * 16;
    char* const lA1 = (char*)Qs[1] + tid * 16;
    char* const lB1 = (char*)Ks[1] + tid * 16;

    const int qRow = (wq * 64 + l16) << 7;
    const int kRow = (wk * 64 + l16) << 7;
    const int cx0  = (g4 << 4) ^ ((l16 & 7) << 4);

    f32x4 acc[4][4];   // [mk(kv subtile)][nq(q subtile)]
    const f32x4 z4 = {0.f, 0.f, 0.f, 0.f};
#pragma unroll
    for (int i = 0; i < 4; ++i)
#pragma unroll
        for (int j = 0; j < 4; ++j) acc[i][j] = z4;

#define STAGE_QK(kt, la, lb) { \
    const u16* ga_ = gA + (kt) * 64; \
    const u16* gb_ = gB + (kt) * 64; \
    GLD16(ga_,            (la)); \
    GLD16(ga_ +  64 * DD, (la) + 8192); \
    GLD16(gb_,            (lb)); \
    GLD16(gb_ +  64 * DD, (lb) + 8192); \
    GLD16(gb_ + 128 * DD, (lb) + 16384); \
    GLD16(gb_ + 192 * DD, (lb) + 24576); }

#define LDQ4(Qb_, kx) { \
    const char* p_ = (const char*)(Qb_) + qRow + ((kx) ? (cx0 ^ 64) : cx0); \
    fq0 = *(const bf16x8*)(p_); \
    fq1 = *(const bf16x8*)(p_ + 2048); \
    fq2 = *(const bf16x8*)(p_ + 4096); \
    fq3 = *(const bf16x8*)(p_ + 6144); }

#define LDK2(Kb_, mh, kx) { \
    const char* p_ = (const char*)(Kb_) + kRow + (mh) * 4096 + ((kx) ? (cx0 ^ 64) : cx0); \
    fk0 = *(const bf16x8*)(p_); \
    fk1 = *(const bf16x8*)(p_ + 2048); }

#define MKROW(mi, fk) \
    acc[mi][0] = __builtin_amdgcn_mfma_f32_16x16x32_bf16(fk, fq0, acc[mi][0],0,0,0); \
    acc[mi][1] = __builtin_amdgcn_mfma_f32_16x16x32_bf16(fk, fq1, acc[mi][1],0,0,0); \
    acc[mi][2] = __builtin_amdgcn_mfma_f32_16x16x32_bf16(fk, fq2, acc[mi][2],0,0,0); \
    acc[mi][3] = __builtin_amdgcn_mfma_f32_16x16x32_bf16(fk, fq3, acc[mi][3],0,0,0);

    STAGE_QK(0, lA0, lB0);
    STAGE_QK(1, lA1, lB1);
    asm volatile("s_waitcnt vmcnt(6)" ::: "memory");
    SCHED0(); __builtin_amdgcn_s_barrier(); SCHED0();

#pragma unroll 1
    for (int it = 0; it < 8; ++it){
        bf16x8 fq0, fq1, fq2, fq3, fk0, fk1;
        // K-tile 2it from buf0
        LDK2(Ks[0], 0, 0); LDQ4(Qs[0], 0);
        PH_PRE(); MKROW(0,fk0) MKROW(1,fk1) PH_POST();
        LDK2(Ks[0], 1, 0);
        PH_PRE(); MKROW(2,fk0) MKROW(3,fk1) PH_POST();
        LDK2(Ks[0], 0, 1); LDQ4(Qs[0], 1);
        PH_PRE(); MKROW(0,fk0) MKROW(1,fk1) PH_POST();
        LDK2(Ks[0], 1, 1);
        PH_PRE(); MKROW(2,fk0) MKROW(3,fk1) PH_POST();
        if (it < 7){
            STAGE_QK(2*it+2, lA0, lB0);
            asm volatile("s_waitcnt vmcnt(6)" ::: "memory");
        } else {
            asm volatile("s_waitcnt vmcnt(0)" ::: "memory");
        }
        SCHED0(); __builtin_amdgcn_s_barrier(); SCHED0();
        // K-tile 2it+1 from buf1
        LDK2(Ks[1], 0, 0); LDQ4(Qs[1], 0);
        PH_PRE(); MKROW(0,fk0) MKROW(1,fk1) PH_POST();
        LDK2(Ks[1], 1, 0);
        PH_PRE(); MKROW(2,fk0) MKROW(3,fk1) PH_POST();
        LDK2(Ks[1], 0, 1); LDQ4(Qs[1], 1);
        PH_PRE(); MKROW(0,fk0) MKROW(1,fk1) PH_POST();
        LDK2(Ks[1], 1, 1);
        PH_PRE(); MKROW(2,fk0) MKROW(3,fk1) PH_POST();
        if (it < 7){
            STAGE_QK(2*it+3, lA1, lB1);
            asm volatile("s_waitcnt vmcnt(6)" ::: "memory");
            SCHED0(); __builtin_amdgcn_s_barrier(); SCHED0();
        }
    }
#undef STAGE_QK
#undef LDQ4
#undef LDK2
#undef MKROW

    // epilogue: per (nq): q-row = l16-indexed; per (mk): 4 consecutive kv.
    // int4 mask load + short4 P store per fragment; rowsum via shfl over g4.
#pragma unroll
    for (int nq = 0; nq < 4; ++nq){
        const int grow = row0 + wq * 64 + nq * 16 + l16;
        const size_t rbase = (size_t)(b * SS + grow) * SS;
        float rs = 0.f;
#pragma unroll
        for (int mk = 0; mk < 4; ++mk){
            const int gcolb = col0 + wk * 64 + mk * 16 + g4 * 4;
            int4v mm = *(const int4v*)&maskg[rbase + gcolb];
            float e0 = mm[0] ? __expf(acc[mk][nq][0]) : 0.f;
            float e1 = mm[1] ? __expf(acc[mk][nq][1]) : 0.f;
            float e2 = mm[2] ? __expf(acc[mk][nq][2]) : 0.f;
            float e3 = mm[3] ? __expf(acc[mk][nq][3]) : 0.f;
            short4v pp;
            pp[0] = (short)f2bf(e0); pp[1] = (short)f2bf(e1);
            pp[2] = (short)f2bf(e2); pp[3] = (short)f2bf(e3);
            *(short4v*)&P[rbase + gcolb] = pp;
            rs += (e0 + e1) + (e2 + e3);
        }
        rs += __shfl_xor(rs, 16);
        rs += __shfl_xor(rs, 32);
        if (g4 == 0) atomicAdd(&rowsum[b * SS + grow], rs);
    }
}

// ---------------- pass 2: X = (P V) / rowsum -> bf16 ----------------
// 256 blocks, 512 threads. 128x256 tile, BK=64, 8-phase counted-vmcnt (kept).
__global__ __launch_bounds__(512, 2) void pv_kernel(
    const u16* __restrict__ P, const u16* __restrict__ Vt,
    const float* __restrict__ rowsum, u16* __restrict__ Xn)
{
    __shared__ __align__(16) u16 As[2][128 * 64];   // 32 KB
    __shared__ __align__(16) u16 Bs[2][256 * 64];   // 64 KB

    const int swz = ((blockIdx.x & 7) << 5) + (blockIdx.x >> 3);
    const int b   = swz >> 6;
    const int bx  = (swz >> 2) & 15;
    const int by  = swz & 3;
    const int row0 = bx << 7, col0 = by << 8;

    const int tid = threadIdx.x;
    const int wid = tid >> 6, lane = tid & 63;
    const int l16 = lane & 15, g4 = lane >> 4;
    const int wr = wid >> 2, wc = wid & 3;

    const int sr   = tid >> 3;
    const int scol = ((tid & 7) ^ (sr & 7)) << 3;
    const u16* gA = P  + (size_t)(b * SS + row0 + sr) * SS + scol;
    const u16* gB = Vt + (size_t)(b * DD + col0 + sr) * SS + scol;
    char* const lA0 = (char*)As[0] + tid * 16;
    char* const lB0 = (char*)Bs[0] + tid * 16;
    char* const lA1 = (char*)As[1] + tid * 16;
    char* const lB1 = (char*)Bs[1] + tid * 16;

    const int aRow = (wr * 64 + l16) << 7;
    const int bRow = (wc * 64 + l16) << 7;
    const int cx0  = (g4 << 4) ^ ((l16 & 7) << 4);

    f32x4 acc[4][4];
    const f32x4 z4 = {0.f, 0.f, 0.f, 0.f};
#pragma unroll
    for (int i = 0; i < 4; ++i)
#pragma unroll
        for (int j = 0; j < 4; ++j) acc[i][j] = z4;

#define STAGE_PV(kt, la, lb) { \
    const u16* ga_ = gA + (kt) * 64; \
    const u16* gb_ = gB + (kt) * 64; \
    GLD16(ga_,            (la)); \
    GLD16(ga_ +  64 * SS, (la) + 8192); \
    GLD16(gb_,            (lb)); \
    GLD16(gb_ +  64 * SS, (lb) + 8192); \
    GLD16(gb_ + 128 * SS, (lb) + 16384); \
    GLD16(gb_ + 192 * SS, (lb) + 24576); }

#define LDA2(Ab_, mh, kx) { \
    const char* p_ = (const char*)(Ab_) + aRow + (mh) * 4096 + ((kx) ? (cx0 ^ 64) : cx0); \
    fa0 = *(const bf16x8*)(p_); \
    fa1 = *(const bf16x8*)(p_ + 2048); }

#define LDB4(Bb_, kx) { \
    const char* p_ = (const char*)(Bb_) + bRow + ((kx) ? (cx0 ^ 64) : cx0); \
    fb0 = *(const bf16x8*)(p_); \
    fb1 = *(const bf16x8*)(p_ + 2048); \
    fb2 = *(const bf16x8*)(p_ + 4096); \
    fb3 = *(const bf16x8*)(p_ + 6144); }

#define MROWP(mi, fa) \
    acc[mi][0] = __builtin_amdgcn_mfma_f32_16x16x32_bf16(fa, fb0, acc[mi][0],0,0,0); \
    acc[mi][1] = __builtin_amdgcn_mfma_f32_16x16x32_bf16(fa, fb1, acc[mi][1],0,0,0); \
    acc[mi][2] = __builtin_amdgcn_mfma_f32_16x16x32_bf16(fa, fb2, acc[mi][2],0,0,0); \
    acc[mi][3] = __builtin_amdgcn_mfma_f32_16x16x32_bf16(fa, fb3, acc[mi][3],0,0,0);

    STAGE_PV(0, lA0, lB0);
    STAGE_PV(1, lA1, lB1);
    asm volatile("s_waitcnt vmcnt(6)" ::: "memory");
    SCHED0(); __builtin_amdgcn_s_barrier(); SCHED0();

#pragma unroll 1
    for (int it = 0; it < 16; ++it){
        bf16x8 fa0, fa1, fb0, fb1, fb2, fb3;
        LDA2(As[0], 0, 0); LDB4(Bs[0], 0);
        PH_PRE(); MROWP(0,fa0) MROWP(1,fa1) PH_POST();
        LDA2(As[0], 1, 0);
        PH_PRE(); MROWP(2,fa0) MROWP(3,fa1) PH_POST();
        LDA2(As[0], 0, 1); LDB4(Bs[0], 1);
        PH_PRE(); MROWP(0,fa0) MROWP(1,fa1) PH_POST();
        LDA2(As[0], 1, 1);
        PH_PRE(); MROWP(2,fa0) MROWP(3,fa1) PH_POST();
        if (it < 15){
            STAGE_PV(2*it+2, lA0, lB0);
            asm volatile("s_waitcnt vmcnt(6)" ::: "memory");
        } else {
            asm volatile("s_waitcnt vmcnt(0)" ::: "memory");
        }
        SCHED0(); __builtin_amdgcn_s_barrier(); SCHED0();
        LDA2(As[1], 0, 0); LDB4(Bs[1], 0);
        PH_PRE(); MROWP(0,fa0) MROWP(1,fa1) PH_POST();
        LDA2(As[1], 1, 0);
        PH_PRE(); MROWP(2,fa0) MROWP(3,fa1) PH_POST();
        LDA2(As[1], 0, 1); LDB4(Bs[1], 1);
        PH_PRE(); MROWP(0,fa0) MROWP(1,fa1) PH_POST();
        LDA2(As[1], 1, 1);
        PH_PRE(); MROWP(2,fa0) MROWP(3,fa1) PH_POST();
        if (it < 15){
            STAGE_PV(2*it+3, lA1, lB1);
            asm volatile("s_waitcnt vmcnt(6)" ::: "memory");
            SCHED0(); __builtin_amdgcn_s_barrier(); SCHED0();
        }
    }
#undef STAGE_PV
#undef LDA2
#undef LDB4
#undef MROWP

#pragma unroll
    for (int m = 0; m < 4; ++m){
        float inv[4];
#pragma unroll
        for (int r = 0; r < 4; ++r)
            inv[r] = 1.f / rowsum[b * SS + row0 + wr * 64 + m * 16 + g4 * 4 + r];
#pragma unroll
        for (int n = 0; n < 4; ++n){
            const int gcol = col0 + wc * 64 + n * 16 + l16;
#pragma unroll
            for (int r = 0; r < 4; ++r){
                const int grow = row0 + wr * 64 + m * 16 + g4 * 4 + r;
                Xn[(size_t)(b * SS + grow) * DD + gcol] = f2bf(acc[m][n][r] * inv[r]);
            }
        }
    }
}

// ---------------- pass 3: LayerNorm over d ----------------
__global__ __launch_bounds__(256) void ln_kernel(
    const u16* __restrict__ Xn, const float* __restrict__ gamma,
    const float* __restrict__ beta, float* __restrict__ out)
{
    __shared__ float red[2][4];
    const int row = blockIdx.x;      // b*S + s
    const int t = threadIdx.x;
    short4v xv = *(const short4v*)&Xn[(size_t)row * DD + t * 4];
    float x[4];
#pragma unroll
    for (int j = 0; j < 4; ++j)
        x[j] = __uint_as_float(((unsigned)(u16)xv[j]) << 16);
    float s  = x[0] + x[1] + x[2] + x[3];
    float sq = x[0]*x[0] + x[1]*x[1] + x[2]*x[2] + x[3]*x[3];
#pragma unroll
    for (int d = 1; d < 64; d <<= 1){ s += __shfl_xor(s, d); sq += __shfl_xor(sq, d); }
    const int wv = t >> 6;
    if ((t & 63) == 0){ red[0][wv] = s; red[1][wv] = sq; }
    __syncthreads();
    float S  = red[0][0] + red[0][1] + red[0][2] + red[0][3];
    float Sq = red[1][0] + red[1][1] + red[1][2] + red[1][3];
    float mu = S * (1.f / 1024.f);
    float var = Sq * (1.f / 1024.f) - mu * mu;
    float rstd = rsqrtf(var + 1e-5f);
    float4v g  = *(const float4v*)&gamma[t * 4];
    float4v be = *(const float4v*)&beta[t * 4];
    float4v o;
#pragma unroll
    for (int j = 0; j < 4; ++j) o[j] = (x[j] - mu) * rstd * g[j] + be[j];
    *(float4v*)&out[(size_t)row * DD + t * 4] = o;
}

extern "C" void kernel_launch(void* const* d_in, const int* in_sizes, int n_in,
                              void* d_out, int out_size, void* d_ws, size_t ws_size,
                              hipStream_t stream) {
    const float* q     = (const float*)d_in[0];
    const float* k     = (const float*)d_in[1];
    const float* v     = (const float*)d_in[2];
    const int*   mask  = (const int*)d_in[3];
    const float* gamma = (const float*)d_in[4];
    const float* beta  = (const float*)d_in[5];
    float* out = (float*)d_out;

    u16* Qb = (u16*)d_ws;                                  // 16 MB (pre-scaled by 1/sqrt(d))
    u16* Kb = Qb + (size_t)BB * SS * DD;                   // 16 MB
    u16* Vt = Kb + (size_t)BB * SS * DD;                   // 16 MB
    u16* P  = Vt + (size_t)BB * SS * DD;                   // 32 MB
    u16* Xn = P  + (size_t)BB * SS * SS;                   // 16 MB
    float* rowsum = (float*)(Xn + (size_t)BB * SS * DD);   // 32 KB

    const int n4 = BB * SS * DD / 4;
    conv_bf16_kernel<<<n4 / 256, 256, 0, stream>>>(q, Qb, n4, 0.03125f);
    conv_bf16_kernel<<<n4 / 256, 256, 0, stream>>>(k, Kb, n4, 1.0f);
    transpose_v_kernel<<<dim3(SS / 64, DD / 64, BB), 256, 0, stream>>>(v, Vt);
    zero_f32<<<BB * SS / 256, 256, 0, stream>>>(rowsum, BB * SS);

    qk_kernel<<<512, 512, 0, stream>>>(Qb, Kb, mask, P, rowsum);
    pv_kernel<<<256, 512, 0, stream>>>(P, Vt, rowsum, Xn);
    ln_kernel<<<BB * SS, 256, 0, stream>>>(Xn, gamma, beta, out);
}

// Round 8
// 152.810 us; speedup vs baseline: 1.0083x; 1.0083x over previous
//
#include <hip/hip_runtime.h>
#include <hip/hip_bf16.h>

typedef unsigned short u16;
typedef unsigned long long u64;
typedef __attribute__((ext_vector_type(8))) short bf16x8;
typedef __attribute__((ext_vector_type(4))) float f32x4;
typedef __attribute__((ext_vector_type(4))) float float4v;
typedef __attribute__((ext_vector_type(4))) short short4v;
typedef __attribute__((ext_vector_type(4))) int int4v;

#define BB 4
#define SS 2048
#define DD 1024

__device__ __forceinline__ u16 f2bf(float x){
    unsigned u = __float_as_uint(x);
    return (u16)((u + 0x7fffu + ((u >> 16) & 1u)) >> 16);  // RNE
}

#define GLD16(g, l) __builtin_amdgcn_global_load_lds( \
    (const __attribute__((address_space(1))) unsigned int*)(g), \
    (__attribute__((address_space(3))) unsigned int*)(l), 16, 0, 0)

#define SCHED0() __builtin_amdgcn_sched_barrier(0)
#define PH_PRE()  SCHED0(); __builtin_amdgcn_s_barrier(); SCHED0(); __builtin_amdgcn_s_setprio(1)
#define PH_POST() __builtin_amdgcn_s_setprio(0); SCHED0(); __builtin_amdgcn_s_barrier(); SCHED0()

// ---------------- prepass: f32 -> bf16 elementwise (optional scale) ----------------
__global__ void conv_bf16_kernel(const float* __restrict__ in,
                                 u16* __restrict__ out, int n4, float scale){
    int i = blockIdx.x * 256 + threadIdx.x;
    if (i >= n4) return;
    float4v v = ((const float4v*)in)[i];
    short4v o;
    o[0] = (short)f2bf(v[0] * scale); o[1] = (short)f2bf(v[1] * scale);
    o[2] = (short)f2bf(v[2] * scale); o[3] = (short)f2bf(v[3] * scale);
    ((short4v*)out)[i] = o;
}

// ---------------- prepass: V [b][s][d] f32 -> Vt [b][d][s] bf16 ----------------
__global__ void transpose_v_kernel(const float* __restrict__ v,
                                   u16* __restrict__ vt){
    __shared__ float tile[64][65];
    const int b  = blockIdx.z;
    const int s0 = blockIdx.x << 6;
    const int d0 = blockIdx.y << 6;
    const int tx = threadIdx.x & 15;
    const int ty = threadIdx.x >> 4;
#pragma unroll
    for (int kk = 0; kk < 4; ++kk){
        const float* p = v + ((b * SS + s0 + ty + 16 * kk) * DD) + d0 + tx * 4;
        float4v val = *(const float4v*)p;
        tile[ty + 16 * kk][tx * 4 + 0] = val[0];
        tile[ty + 16 * kk][tx * 4 + 1] = val[1];
        tile[ty + 16 * kk][tx * 4 + 2] = val[2];
        tile[ty + 16 * kk][tx * 4 + 3] = val[3];
    }
    __syncthreads();
#pragma unroll
    for (int kk = 0; kk < 4; ++kk){
        int dy = ty + 16 * kk;
        short4v o;
        o[0] = (short)f2bf(tile[tx * 4 + 0][dy]);
        o[1] = (short)f2bf(tile[tx * 4 + 1][dy]);
        o[2] = (short)f2bf(tile[tx * 4 + 2][dy]);
        o[3] = (short)f2bf(tile[tx * 4 + 3][dy]);
        *(short4v*)&vt[((b * DD + d0 + dy) * SS) + s0 + tx * 4] = o;
    }
}

__global__ void zero_f32(float* __restrict__ p, int n){
    int i = blockIdx.x * 256 + threadIdx.x;
    if (i < n) p[i] = 0.f;
}

// ---------------- prepass: mask int32 -> bitmask (64 MB -> 2 MB) ----------------
// thread i produces bits[i] = 32 mask ints, streamed coalesced at full BW.
__global__ __launch_bounds__(256) void mask_pack_kernel(
    const int* __restrict__ m, unsigned int* __restrict__ bits){
    const int i = blockIdx.x * 256 + threadIdx.x;      // u32 index
    const int4v* p = (const int4v*)m + (size_t)i * 8;
    unsigned w = 0;
#pragma unroll
    for (int j = 0; j < 8; ++j){
        int4v v = p[j];
        w |= (unsigned)(v[0] != 0) << (j * 4 + 0);
        w |= (unsigned)(v[1] != 0) << (j * 4 + 1);
        w |= (unsigned)(v[2] != 0) << (j * 4 + 2);
        w |= (unsigned)(v[3] != 0) << (j * 4 + 3);
    }
    bits[i] = w;
}

// ---------------- pass 1: S^T-frag = K Q^T -> bitmask/exp -> P bf16, rowsum ----------------
// 1024 blocks, 256 threads (4 waves, q2 x kv2). 128 q x 128 kv tile, BK=64,
// 8-phase counted-vmcnt, T2 swizzle, T5 setprio, swapped MFMA operands.
// LDS 64 KB -> 2 blocks/CU: one block's epilogue overlaps the other's main loop.
__global__ __launch_bounds__(256, 2) void qk_kernel(
    const u16* __restrict__ Qb, const u16* __restrict__ Kb,
    const u64* __restrict__ mbits, u16* __restrict__ P,
    float* __restrict__ rowsum)
{
    __shared__ __align__(16) u16 Qs[2][128 * 64];   // 32 KB
    __shared__ __align__(16) u16 Ks[2][128 * 64];   // 32 KB

    const int swz = ((blockIdx.x & 7) << 7) + (blockIdx.x >> 3);  // 1024, bijective
    const int b   = swz >> 8;
    const int bx  = (swz >> 4) & 15;    // 16 q-row tiles of 128
    const int by  = swz & 15;           // 16 kv tiles of 128
    const int row0 = bx << 7, col0 = by << 7;

    const int tid = threadIdx.x;
    const int wid = tid >> 6, lane = tid & 63;
    const int l16 = lane & 15, g4 = lane >> 4;
    const int wq = wid >> 1, wk = wid & 1;   // q[wq*64,+64) x kv[wk*64,+64)

    const int sr   = tid >> 3;                     // 0..31
    const int scol = ((tid & 7) ^ (sr & 7)) << 3;  // pre-swizzled source col
    const u16* gA = Qb + (size_t)(b * SS + row0 + sr) * DD + scol;
    const u16* gB = Kb + (size_t)(b * SS + col0 + sr) * DD + scol;
    char* const lA0 = (char*)Qs[0] + tid * 16;
    char* const lB0 = (char*)Ks[0] + tid * 16;
    char* const lA1 = (char*)Qs[1] + tid * 16;
    char* const lB1 = (char*)Ks[1] + tid * 16;

    const int qRow = (wq * 64 + l16) << 7;
    const int kRow = (wk * 64 + l16) << 7;
    const int cx0  = (g4 << 4) ^ ((l16 & 7) << 4);

    f32x4 acc[4][4];   // [mk][nq]
    const f32x4 z4 = {0.f, 0.f, 0.f, 0.f};
#pragma unroll
    for (int i = 0; i < 4; ++i)
#pragma unroll
        for (int j = 0; j < 4; ++j) acc[i][j] = z4;

#define STAGE_QK(kt, la, lb) { \
    const u16* ga_ = gA + (kt) * 64; \
    const u16* gb_ = gB + (kt) * 64; \
    GLD16(ga_,            (la)); \
    GLD16(ga_ + 32 * DD,  (la) + 4096); \
    GLD16(ga_ + 64 * DD,  (la) + 8192); \
    GLD16(ga_ + 96 * DD,  (la) + 12288); \
    GLD16(gb_,            (lb)); \
    GLD16(gb_ + 32 * DD,  (lb) + 4096); \
    GLD16(gb_ + 64 * DD,  (lb) + 8192); \
    GLD16(gb_ + 96 * DD,  (lb) + 12288); }

#define LDQ4(Qb_, kx) { \
    const char* p_ = (const char*)(Qb_) + qRow + ((kx) ? (cx0 ^ 64) : cx0); \
    fq0 = *(const bf16x8*)(p_); \
    fq1 = *(const bf16x8*)(p_ + 2048); \
    fq2 = *(const bf16x8*)(p_ + 4096); \
    fq3 = *(const bf16x8*)(p_ + 6144); }

#define LDK2(Kb_, mh, kx) { \
    const char* p_ = (const char*)(Kb_) + kRow + (mh) * 4096 + ((kx) ? (cx0 ^ 64) : cx0); \
    fk0 = *(const bf16x8*)(p_); \
    fk1 = *(const bf16x8*)(p_ + 2048); }

#define MKROW(mi, fk) \
    acc[mi][0] = __builtin_amdgcn_mfma_f32_16x16x32_bf16(fk, fq0, acc[mi][0],0,0,0); \
    acc[mi][1] = __builtin_amdgcn_mfma_f32_16x16x32_bf16(fk, fq1, acc[mi][1],0,0,0); \
    acc[mi][2] = __builtin_amdgcn_mfma_f32_16x16x32_bf16(fk, fq2, acc[mi][2],0,0,0); \
    acc[mi][3] = __builtin_amdgcn_mfma_f32_16x16x32_bf16(fk, fq3, acc[mi][3],0,0,0);

    STAGE_QK(0, lA0, lB0);
    STAGE_QK(1, lA1, lB1);
    asm volatile("s_waitcnt vmcnt(8)" ::: "memory");
    SCHED0(); __builtin_amdgcn_s_barrier(); SCHED0();

#pragma unroll 1
    for (int it = 0; it < 8; ++it){
        bf16x8 fq0, fq1, fq2, fq3, fk0, fk1;
        // K-tile 2it from buf0
        LDK2(Ks[0], 0, 0); LDQ4(Qs[0], 0);
        PH_PRE(); MKROW(0,fk0) MKROW(1,fk1) PH_POST();
        LDK2(Ks[0], 1, 0);
        PH_PRE(); MKROW(2,fk0) MKROW(3,fk1) PH_POST();
        LDK2(Ks[0], 0, 1); LDQ4(Qs[0], 1);
        PH_PRE(); MKROW(0,fk0) MKROW(1,fk1) PH_POST();
        LDK2(Ks[0], 1, 1);
        PH_PRE(); MKROW(2,fk0) MKROW(3,fk1) PH_POST();
        if (it < 7){
            STAGE_QK(2*it+2, lA0, lB0);
            asm volatile("s_waitcnt vmcnt(8)" ::: "memory");
        } else {
            asm volatile("s_waitcnt vmcnt(0)" ::: "memory");
        }
        SCHED0(); __builtin_amdgcn_s_barrier(); SCHED0();
        // K-tile 2it+1 from buf1
        LDK2(Ks[1], 0, 0); LDQ4(Qs[1], 0);
        PH_PRE(); MKROW(0,fk0) MKROW(1,fk1) PH_POST();
        LDK2(Ks[1], 1, 0);
        PH_PRE(); MKROW(2,fk0) MKROW(3,fk1) PH_POST();
        LDK2(Ks[1], 0, 1); LDQ4(Qs[1], 1);
        PH_PRE(); MKROW(0,fk0) MKROW(1,fk1) PH_POST();
        LDK2(Ks[1], 1, 1);
        PH_PRE(); MKROW(2,fk0) MKROW(3,fk1) PH_POST();
        if (it < 7){
            STAGE_QK(2*it+3, lA1, lB1);
            asm volatile("s_waitcnt vmcnt(8)" ::: "memory");
            SCHED0(); __builtin_amdgcn_s_barrier(); SCHED0();
        }
    }
#undef STAGE_QK
#undef LDQ4
#undef LDK2
#undef MKROW

    // epilogue: one u64 bitmask window per (nq); 4 consecutive kv per fragment.
#pragma unroll
    for (int nq = 0; nq < 4; ++nq){
        const int grow = row0 + wq * 64 + nq * 16 + l16;
        const size_t rbase = (size_t)(b * SS + grow) * SS;
        const u64 w64 = mbits[(size_t)(b * SS + grow) * 32 + by * 2 + wk];
        float rs = 0.f;
#pragma unroll
        for (int mk = 0; mk < 4; ++mk){
            const int bit0 = mk * 16 + g4 * 4;
            const int gcolb = col0 + wk * 64 + bit0;
            float e0 = ((w64 >> (bit0 + 0)) & 1ull) ? __expf(acc[mk][nq][0]) : 0.f;
            float e1 = ((w64 >> (bit0 + 1)) & 1ull) ? __expf(acc[mk][nq][1]) : 0.f;
            float e2 = ((w64 >> (bit0 + 2)) & 1ull) ? __expf(acc[mk][nq][2]) : 0.f;
            float e3 = ((w64 >> (bit0 + 3)) & 1ull) ? __expf(acc[mk][nq][3]) : 0.f;
            short4v pp;
            pp[0] = (short)f2bf(e0); pp[1] = (short)f2bf(e1);
            pp[2] = (short)f2bf(e2); pp[3] = (short)f2bf(e3);
            *(short4v*)&P[rbase + gcolb] = pp;
            rs += (e0 + e1) + (e2 + e3);
        }
        rs += __shfl_xor(rs, 16);
        rs += __shfl_xor(rs, 32);
        if (g4 == 0) atomicAdd(&rowsum[b * SS + grow], rs);
    }
}

// ---------------- pass 2: X = (P V) / rowsum -> bf16 ----------------
// 256 blocks, 512 threads. 128x256 tile, BK=64, 8-phase counted-vmcnt (kept).
__global__ __launch_bounds__(512, 2) void pv_kernel(
    const u16* __restrict__ P, const u16* __restrict__ Vt,
    const float* __restrict__ rowsum, u16* __restrict__ Xn)
{
    __shared__ __align__(16) u16 As[2][128 * 64];   // 32 KB
    __shared__ __align__(16) u16 Bs[2][256 * 64];   // 64 KB

    const int swz = ((blockIdx.x & 7) << 5) + (blockIdx.x >> 3);
    const int b   = swz >> 6;
    const int bx  = (swz >> 2) & 15;
    const int by  = swz & 3;
    const int row0 = bx << 7, col0 = by << 8;

    const int tid = threadIdx.x;
    const int wid = tid >> 6, lane = tid & 63;
    const int l16 = lane & 15, g4 = lane >> 4;
    const int wr = wid >> 2, wc = wid & 3;

    const int sr   = tid >> 3;
    const int scol = ((tid & 7) ^ (sr & 7)) << 3;
    const u16* gA = P  + (size_t)(b * SS + row0 + sr) * SS + scol;
    const u16* gB = Vt + (size_t)(b * DD + col0 + sr) * SS + scol;
    char* const lA0 = (char*)As[0] + tid * 16;
    char* const lB0 = (char*)Bs[0] + tid * 16;
    char* const lA1 = (char*)As[1] + tid * 16;
    char* const lB1 = (char*)Bs[1] + tid * 16;

    const int aRow = (wr * 64 + l16) << 7;
    const int bRow = (wc * 64 + l16) << 7;
    const int cx0  = (g4 << 4) ^ ((l16 & 7) << 4);

    f32x4 acc[4][4];
    const f32x4 z4 = {0.f, 0.f, 0.f, 0.f};
#pragma unroll
    for (int i = 0; i < 4; ++i)
#pragma unroll
        for (int j = 0; j < 4; ++j) acc[i][j] = z4;

#define STAGE_PV(kt, la, lb) { \
    const u16* ga_ = gA + (kt) * 64; \
    const u16* gb_ = gB + (kt) * 64; \
    GLD16(ga_,            (la)); \
    GLD16(ga_ +  64 * SS, (la) + 8192); \
    GLD16(gb_,            (lb)); \
    GLD16(gb_ +  64 * SS, (lb) + 8192); \
    GLD16(gb_ + 128 * SS, (lb) + 16384); \
    GLD16(gb_ + 192 * SS, (lb) + 24576); }

#define LDA2(Ab_, mh, kx) { \
    const char* p_ = (const char*)(Ab_) + aRow + (mh) * 4096 + ((kx) ? (cx0 ^ 64) : cx0); \
    fa0 = *(const bf16x8*)(p_); \
    fa1 = *(const bf16x8*)(p_ + 2048); }

#define LDB4(Bb_, kx) { \
    const char* p_ = (const char*)(Bb_) + bRow + ((kx) ? (cx0 ^ 64) : cx0); \
    fb0 = *(const bf16x8*)(p_); \
    fb1 = *(const bf16x8*)(p_ + 2048); \
    fb2 = *(const bf16x8*)(p_ + 4096); \
    fb3 = *(const bf16x8*)(p_ + 6144); }

#define MROWP(mi, fa) \
    acc[mi][0] = __builtin_amdgcn_mfma_f32_16x16x32_bf16(fa, fb0, acc[mi][0],0,0,0); \
    acc[mi][1] = __builtin_amdgcn_mfma_f32_16x16x32_bf16(fa, fb1, acc[mi][1],0,0,0); \
    acc[mi][2] = __builtin_amdgcn_mfma_f32_16x16x32_bf16(fa, fb2, acc[mi][2],0,0,0); \
    acc[mi][3] = __builtin_amdgcn_mfma_f32_16x16x32_bf16(fa, fb3, acc[mi][3],0,0,0);

    STAGE_PV(0, lA0, lB0);
    STAGE_PV(1, lA1, lB1);
    asm volatile("s_waitcnt vmcnt(6)" ::: "memory");
    SCHED0(); __builtin_amdgcn_s_barrier(); SCHED0();

#pragma unroll 1
    for (int it = 0; it < 16; ++it){
        bf16x8 fa0, fa1, fb0, fb1, fb2, fb3;
        LDA2(As[0], 0, 0); LDB4(Bs[0], 0);
        PH_PRE(); MROWP(0,fa0) MROWP(1,fa1) PH_POST();
        LDA2(As[0], 1, 0);
        PH_PRE(); MROWP(2,fa0) MROWP(3,fa1) PH_POST();
        LDA2(As[0], 0, 1); LDB4(Bs[0], 1);
        PH_PRE(); MROWP(0,fa0) MROWP(1,fa1) PH_POST();
        LDA2(As[0], 1, 1);
        PH_PRE(); MROWP(2,fa0) MROWP(3,fa1) PH_POST();
        if (it < 15){
            STAGE_PV(2*it+2, lA0, lB0);
            asm volatile("s_waitcnt vmcnt(6)" ::: "memory");
        } else {
            asm volatile("s_waitcnt vmcnt(0)" ::: "memory");
        }
        SCHED0(); __builtin_amdgcn_s_barrier(); SCHED0();
        LDA2(As[1], 0, 0); LDB4(Bs[1], 0);
        PH_PRE(); MROWP(0,fa0) MROWP(1,fa1) PH_POST();
        LDA2(As[1], 1, 0);
        PH_PRE(); MROWP(2,fa0) MROWP(3,fa1) PH_POST();
        LDA2(As[1], 0, 1); LDB4(Bs[1], 1);
        PH_PRE(); MROWP(0,fa0) MROWP(1,fa1) PH_POST();
        LDA2(As[1], 1, 1);
        PH_PRE(); MROWP(2,fa0) MROWP(3,fa1) PH_POST();
        if (it < 15){
            STAGE_PV(2*it+3, lA1, lB1);
            asm volatile("s_waitcnt vmcnt(6)" ::: "memory");
            SCHED0(); __builtin_amdgcn_s_barrier(); SCHED0();
        }
    }
#undef STAGE_PV
#undef LDA2
#undef LDB4
#undef MROWP

#pragma unroll
    for (int m = 0; m < 4; ++m){
        float inv[4];
#pragma unroll
        for (int r = 0; r < 4; ++r)
            inv[r] = 1.f / rowsum[b * SS + row0 + wr * 64 + m * 16 + g4 * 4 + r];
#pragma unroll
        for (int n = 0; n < 4; ++n){
            const int gcol = col0 + wc * 64 + n * 16 + l16;
#pragma unroll
            for (int r = 0; r < 4; ++r){
                const int grow = row0 + wr * 64 + m * 16 + g4 * 4 + r;
                Xn[(size_t)(b * SS + grow) * DD + gcol] = f2bf(acc[m][n][r] * inv[r]);
            }
        }
    }
}

// ---------------- pass 3: LayerNorm over d ----------------
__global__ __launch_bounds__(256) void ln_kernel(
    const u16* __restrict__ Xn, const float* __restrict__ gamma,
    const float* __restrict__ beta, float* __restrict__ out)
{
    __shared__ float red[2][4];
    const int row = blockIdx.x;      // b*S + s
    const int t = threadIdx.x;
    short4v xv = *(const short4v*)&Xn[(size_t)row * DD + t * 4];
    float x[4];
#pragma unroll
    for (int j = 0; j < 4; ++j)
        x[j] = __uint_as_float(((unsigned)(u16)xv[j]) << 16);
    float s  = x[0] + x[1] + x[2] + x[3];
    float sq = x[0]*x[0] + x[1]*x[1] + x[2]*x[2] + x[3]*x[3];
#pragma unroll
    for (int d = 1; d < 64; d <<= 1){ s += __shfl_xor(s, d); sq += __shfl_xor(sq, d); }
    const int wv = t >> 6;
    if ((t & 63) == 0){ red[0][wv] = s; red[1][wv] = sq; }
    __syncthreads();
    float S  = red[0][0] + red[0][1] + red[0][2] + red[0][3];
    float Sq = red[1][0] + red[1][1] + red[1][2] + red[1][3];
    float mu = S * (1.f / 1024.f);
    float var = Sq * (1.f / 1024.f) - mu * mu;
    float rstd = rsqrtf(var + 1e-5f);
    float4v g  = *(const float4v*)&gamma[t * 4];
    float4v be = *(const float4v*)&beta[t * 4];
    float4v o;
#pragma unroll
    for (int j = 0; j < 4; ++j) o[j] = (x[j] - mu) * rstd * g[j] + be[j];
    *(float4v*)&out[(size_t)row * DD + t * 4] = o;
}

extern "C" void kernel_launch(void* const* d_in, const int* in_sizes, int n_in,
                              void* d_out, int out_size, void* d_ws, size_t ws_size,
                              hipStream_t stream) {
    const float* q     = (const float*)d_in[0];
    const float* k     = (const float*)d_in[1];
    const float* v     = (const float*)d_in[2];
    const int*   mask  = (const int*)d_in[3];
    const float* gamma = (const float*)d_in[4];
    const float* beta  = (const float*)d_in[5];
    float* out = (float*)d_out;

    u16* Qb = (u16*)d_ws;                                  // 16 MB (pre-scaled by 1/sqrt(d))
    u16* Kb = Qb + (size_t)BB * SS * DD;                   // 16 MB
    u16* Vt = Kb + (size_t)BB * SS * DD;                   // 16 MB
    u16* P  = Vt + (size_t)BB * SS * DD;                   // 32 MB
    u16* Xn = P  + (size_t)BB * SS * SS;                   // 16 MB
    float* rowsum = (float*)(Xn + (size_t)BB * SS * DD);   // 32 KB
    // bitmask (2 MB) aliases the Xn region: written by mask_pack, consumed by
    // qk, then Xn is overwritten by pv (strictly after qk on the same stream).
    unsigned int* mbits = (unsigned int*)Xn;

    const int n4 = BB * SS * DD / 4;
    conv_bf16_kernel<<<n4 / 256, 256, 0, stream>>>(q, Qb, n4, 0.03125f);
    conv_bf16_kernel<<<n4 / 256, 256, 0, stream>>>(k, Kb, n4, 1.0f);
    transpose_v_kernel<<<dim3(SS / 64, DD / 64, BB), 256, 0, stream>>>(v, Vt);
    zero_f32<<<BB * SS / 256, 256, 0, stream>>>(rowsum, BB * SS);
    mask_pack_kernel<<<(BB * SS * SS / 32) / 256, 256, 0, stream>>>(mask, mbits);

    qk_kernel<<<1024, 256, 0, stream>>>(Qb, Kb, (const u64*)mbits, P, rowsum);
    pv_kernel<<<256, 512, 0, stream>>>(P, Vt, rowsum, Xn);
    ln_kernel<<<BB * SS, 256, 0, stream>>>(Xn, gamma, beta, out);
}

// Round 9
// 139.478 us; speedup vs baseline: 1.1046x; 1.0956x over previous
//
#include <hip/hip_runtime.h>
#include <hip/hip_bf16.h>

typedef unsigned short u16;
typedef unsigned long long u64;
typedef __attribute__((ext_vector_type(8))) short bf16x8;
typedef __attribute__((ext_vector_type(4))) float f32x4;
typedef __attribute__((ext_vector_type(4))) float float4v;
typedef __attribute__((ext_vector_type(4))) short short4v;
typedef __attribute__((ext_vector_type(4))) int int4v;

#define BB 4
#define SS 2048
#define DD 1024

__device__ __forceinline__ u16 f2bf(float x){
    unsigned u = __float_as_uint(x);
    return (u16)((u + 0x7fffu + ((u >> 16) & 1u)) >> 16);  // RNE
}

#define GLD16(g, l) __builtin_amdgcn_global_load_lds( \
    (const __attribute__((address_space(1))) unsigned int*)(g), \
    (__attribute__((address_space(3))) unsigned int*)(l), 16, 0, 0)

#define SCHED0() __builtin_amdgcn_sched_barrier(0)
#define PH_PRE()  SCHED0(); __builtin_amdgcn_s_barrier(); SCHED0(); __builtin_amdgcn_s_setprio(1)
#define PH_POST() __builtin_amdgcn_s_setprio(0); SCHED0(); __builtin_amdgcn_s_barrier(); SCHED0()

// ---------------- fused prep: conv Q (scaled), conv K, transpose V, mask_pack, zero ----------------
// grid sections (256 threads each):
//   [0,2048)      conv Q -> bf16 * 1/32
//   [2048,4096)   conv K -> bf16
//   [4096,6144)   transpose V -> Vt bf16
//   [6144,8192)   mask -> bitmask (64MB -> 2MB)
//   [8192,8224)   zero rowsum
__global__ __launch_bounds__(256) void prep_kernel(
    const float* __restrict__ q, const float* __restrict__ k,
    const float* __restrict__ v, const int* __restrict__ mask,
    u16* __restrict__ Qb, u16* __restrict__ Kb, u16* __restrict__ Vt,
    unsigned int* __restrict__ mbits, float* __restrict__ rowsum)
{
    const int bid = blockIdx.x;
    const int tid = threadIdx.x;

    if (bid < 4096){                         // conv Q or K (16 f32/thread)
        const float* in = (bid < 2048) ? q : k;
        u16* out = (bid < 2048) ? Qb : Kb;
        const float scale = (bid < 2048) ? 0.03125f : 1.0f;
        const int sb = bid & 2047;
#pragma unroll
        for (int kk = 0; kk < 4; ++kk){
            int i = sb * 1024 + kk * 256 + tid;      // float4 index
            float4v val = ((const float4v*)in)[i];
            short4v o;
            o[0] = (short)f2bf(val[0] * scale); o[1] = (short)f2bf(val[1] * scale);
            o[2] = (short)f2bf(val[2] * scale); o[3] = (short)f2bf(val[3] * scale);
            ((short4v*)out)[i] = o;
        }
    } else if (bid < 6144){                  // transpose V
        __shared__ float tile[64][65];
        const int sb = bid - 4096;           // 2048 = 4b x 32 s0 x 16 d0
        const int b  = sb >> 9;
        const int r  = sb & 511;
        const int s0 = (r >> 4) << 6;
        const int d0 = (r & 15) << 6;
        const int tx = tid & 15;
        const int ty = tid >> 4;
#pragma unroll
        for (int kk = 0; kk < 4; ++kk){
            const float* p = v + ((size_t)(b * SS + s0 + ty + 16 * kk) * DD) + d0 + tx * 4;
            float4v val = *(const float4v*)p;
            tile[ty + 16 * kk][tx * 4 + 0] = val[0];
            tile[ty + 16 * kk][tx * 4 + 1] = val[1];
            tile[ty + 16 * kk][tx * 4 + 2] = val[2];
            tile[ty + 16 * kk][tx * 4 + 3] = val[3];
        }
        __syncthreads();
#pragma unroll
        for (int kk = 0; kk < 4; ++kk){
            int dy = ty + 16 * kk;
            short4v o;
            o[0] = (short)f2bf(tile[tx * 4 + 0][dy]);
            o[1] = (short)f2bf(tile[tx * 4 + 1][dy]);
            o[2] = (short)f2bf(tile[tx * 4 + 2][dy]);
            o[3] = (short)f2bf(tile[tx * 4 + 3][dy]);
            *(short4v*)&Vt[((size_t)(b * DD + d0 + dy) * SS) + s0 + tx * 4] = o;
        }
    } else if (bid < 8192){                  // mask_pack
        const int i = (bid - 6144) * 256 + tid;          // u32 index
        const int4v* p = (const int4v*)mask + (size_t)i * 8;
        unsigned w = 0;
#pragma unroll
        for (int j = 0; j < 8; ++j){
            int4v vv = p[j];
            w |= (unsigned)(vv[0] != 0) << (j * 4 + 0);
            w |= (unsigned)(vv[1] != 0) << (j * 4 + 1);
            w |= (unsigned)(vv[2] != 0) << (j * 4 + 2);
            w |= (unsigned)(vv[3] != 0) << (j * 4 + 3);
        }
        mbits[i] = w;
    } else {                                  // zero rowsum
        rowsum[(bid - 8192) * 256 + tid] = 0.f;
    }
}

// ---------------- pass 1: S^T-frag = K Q^T -> bitmask/exp -> P bf16, rowsum ----------------
// 256 blocks (1/CU), 512 threads (8 waves: 2 q x 4 kv). 256 q x 256 kv tile, BK=64,
// 8-phase counted-vmcnt, T2 swizzle, T5 setprio, swapped MFMA operands (A=K, B=Q):
// lane holds 4 consecutive kv for one q-row -> u64 bit window + short4 P stores.
__global__ __launch_bounds__(512, 2) void qk_kernel(
    const u16* __restrict__ Qb, const u16* __restrict__ Kb,
    const u64* __restrict__ mbits, u16* __restrict__ P,
    float* __restrict__ rowsum)
{
    __shared__ __align__(16) u16 As[2][256 * 64];   // K tile (kv rows x k)  64 KB
    __shared__ __align__(16) u16 Bs[2][256 * 64];   // Q tile (q rows x k)   64 KB

    const int swz = ((blockIdx.x & 7) << 5) + (blockIdx.x >> 3);  // 256, bijective
    const int b   = swz >> 6;
    const int bx  = (swz >> 3) & 7;     // q-tile
    const int by  = swz & 7;            // kv-tile
    const int row0 = bx << 8, col0 = by << 8;

    const int tid = threadIdx.x;
    const int wid = tid >> 6, lane = tid & 63;
    const int l16 = lane & 15, g4 = lane >> 4;
    const int wq = wid >> 2, wk = wid & 3;   // q[wq*128,+128) x kv[wk*64,+64)

    const int sr   = tid >> 3;                     // 0..63
    const int scol = ((tid & 7) ^ (sr & 7)) << 3;  // pre-swizzled source col
    const u16* gA = Kb + (size_t)(b * SS + col0 + sr) * DD + scol;   // A = K
    const u16* gB = Qb + (size_t)(b * SS + row0 + sr) * DD + scol;   // B = Q
    char* const lA0 = (char*)As[0] + tid * 16;
    char* const lB0 = (char*)Bs[0] + tid * 16;
    char* const lA1 = (char*)As[1] + tid * 16;
    char* const lB1 = (char*)Bs[1] + tid * 16;

    const int kRow = (wk * 64  + l16) << 7;   // A-frag base (kv)
    const int qRow = (wq * 128 + l16) << 7;   // B-frag base (q); +nq*2048
    const int cx0  = (g4 << 4) ^ ((l16 & 7) << 4);

    f32x4 acc[4][8];   // [mk(kv sub)][nq(q sub)]
    const f32x4 z4 = {0.f, 0.f, 0.f, 0.f};
#pragma unroll
    for (int i = 0; i < 4; ++i)
#pragma unroll
        for (int j = 0; j < 8; ++j) acc[i][j] = z4;

#define STAGE_QK(kt, la, lb) { \
    const u16* ga_ = gA + (kt) * 64; \
    const u16* gb_ = gB + (kt) * 64; \
    GLD16(ga_,            (la)); \
    GLD16(ga_ +  64 * DD, (la) + 8192); \
    GLD16(ga_ + 128 * DD, (la) + 16384); \
    GLD16(ga_ + 192 * DD, (la) + 24576); \
    GLD16(gb_,            (lb)); \
    GLD16(gb_ +  64 * DD, (lb) + 8192); \
    GLD16(gb_ + 128 * DD, (lb) + 16384); \
    GLD16(gb_ + 192 * DD, (lb) + 24576); }

#define LDQ8(Bb_, kx) { \
    const char* p_ = (const char*)(Bb_) + qRow + ((kx) ? (cx0 ^ 64) : cx0); \
    fq0 = *(const bf16x8*)(p_);          fq1 = *(const bf16x8*)(p_ + 2048); \
    fq2 = *(const bf16x8*)(p_ + 4096);   fq3 = *(const bf16x8*)(p_ + 6144); \
    fq4 = *(const bf16x8*)(p_ + 8192);   fq5 = *(const bf16x8*)(p_ + 10240); \
    fq6 = *(const bf16x8*)(p_ + 12288);  fq7 = *(const bf16x8*)(p_ + 14336); }

#define LDK2(Ab_, mh, kx) { \
    const char* p_ = (const char*)(Ab_) + kRow + (mh) * 4096 + ((kx) ? (cx0 ^ 64) : cx0); \
    fk0 = *(const bf16x8*)(p_); \
    fk1 = *(const bf16x8*)(p_ + 2048); }

#define MKROW(mi, fk) \
    acc[mi][0] = __builtin_amdgcn_mfma_f32_16x16x32_bf16(fk, fq0, acc[mi][0],0,0,0); \
    acc[mi][1] = __builtin_amdgcn_mfma_f32_16x16x32_bf16(fk, fq1, acc[mi][1],0,0,0); \
    acc[mi][2] = __builtin_amdgcn_mfma_f32_16x16x32_bf16(fk, fq2, acc[mi][2],0,0,0); \
    acc[mi][3] = __builtin_amdgcn_mfma_f32_16x16x32_bf16(fk, fq3, acc[mi][3],0,0,0); \
    acc[mi][4] = __builtin_amdgcn_mfma_f32_16x16x32_bf16(fk, fq4, acc[mi][4],0,0,0); \
    acc[mi][5] = __builtin_amdgcn_mfma_f32_16x16x32_bf16(fk, fq5, acc[mi][5],0,0,0); \
    acc[mi][6] = __builtin_amdgcn_mfma_f32_16x16x32_bf16(fk, fq6, acc[mi][6],0,0,0); \
    acc[mi][7] = __builtin_amdgcn_mfma_f32_16x16x32_bf16(fk, fq7, acc[mi][7],0,0,0);

    STAGE_QK(0, lA0, lB0);
    STAGE_QK(1, lA1, lB1);
    asm volatile("s_waitcnt vmcnt(8)" ::: "memory");
    SCHED0(); __builtin_amdgcn_s_barrier(); SCHED0();

#pragma unroll 1
    for (int it = 0; it < 8; ++it){
        bf16x8 fq0, fq1, fq2, fq3, fq4, fq5, fq6, fq7, fk0, fk1;
        // ---- K-tile 2it from buf0 ----
        LDK2(As[0], 0, 0); LDQ8(Bs[0], 0);
        PH_PRE(); MKROW(0,fk0) MKROW(1,fk1) PH_POST();
        LDK2(As[0], 1, 0);
        PH_PRE(); MKROW(2,fk0) MKROW(3,fk1) PH_POST();
        LDK2(As[0], 0, 1); LDQ8(Bs[0], 1);
        PH_PRE(); MKROW(0,fk0) MKROW(1,fk1) PH_POST();
        LDK2(As[0], 1, 1);
        PH_PRE(); MKROW(2,fk0) MKROW(3,fk1) PH_POST();
        if (it < 7){
            STAGE_QK(2*it+2, lA0, lB0);
            asm volatile("s_waitcnt vmcnt(8)" ::: "memory");
        } else {
            asm volatile("s_waitcnt vmcnt(0)" ::: "memory");
        }
        SCHED0(); __builtin_amdgcn_s_barrier(); SCHED0();
        // ---- K-tile 2it+1 from buf1 ----
        LDK2(As[1], 0, 0); LDQ8(Bs[1], 0);
        PH_PRE(); MKROW(0,fk0) MKROW(1,fk1) PH_POST();
        LDK2(As[1], 1, 0);
        PH_PRE(); MKROW(2,fk0) MKROW(3,fk1) PH_POST();
        LDK2(As[1], 0, 1); LDQ8(Bs[1], 1);
        PH_PRE(); MKROW(0,fk0) MKROW(1,fk1) PH_POST();
        LDK2(As[1], 1, 1);
        PH_PRE(); MKROW(2,fk0) MKROW(3,fk1) PH_POST();
        if (it < 7){
            STAGE_QK(2*it+3, lA1, lB1);
            asm volatile("s_waitcnt vmcnt(8)" ::: "memory");
            SCHED0(); __builtin_amdgcn_s_barrier(); SCHED0();
        }
    }
#undef STAGE_QK
#undef LDQ8
#undef LDK2
#undef MKROW

    // epilogue: per nq one u64 bit window; per (nq,mk) 4 consecutive kv -> short4.
#pragma unroll
    for (int nq = 0; nq < 8; ++nq){
        const int grow = row0 + wq * 128 + nq * 16 + l16;
        const size_t rbase = (size_t)(b * SS + grow) * SS;
        const u64 w64 = mbits[(size_t)(b * SS + grow) * 32 + by * 4 + wk];
        float rs = 0.f;
#pragma unroll
        for (int mk = 0; mk < 4; ++mk){
            const int bit0 = mk * 16 + g4 * 4;
            const int gcolb = col0 + wk * 64 + bit0;
            float e0 = ((w64 >> (bit0 + 0)) & 1ull) ? __expf(acc[mk][nq][0]) : 0.f;
            float e1 = ((w64 >> (bit0 + 1)) & 1ull) ? __expf(acc[mk][nq][1]) : 0.f;
            float e2 = ((w64 >> (bit0 + 2)) & 1ull) ? __expf(acc[mk][nq][2]) : 0.f;
            float e3 = ((w64 >> (bit0 + 3)) & 1ull) ? __expf(acc[mk][nq][3]) : 0.f;
            short4v pp;
            pp[0] = (short)f2bf(e0); pp[1] = (short)f2bf(e1);
            pp[2] = (short)f2bf(e2); pp[3] = (short)f2bf(e3);
            *(short4v*)&P[rbase + gcolb] = pp;
            rs += (e0 + e1) + (e2 + e3);
        }
        rs += __shfl_xor(rs, 16);
        rs += __shfl_xor(rs, 32);
        if (g4 == 0) atomicAdd(&rowsum[b * SS + grow], rs);
    }
}

// ---------------- pass 2: X = (P V) / rowsum -> bf16 ----------------
// 256 blocks, 512 threads. 128x256 tile, BK=64, 8-phase counted-vmcnt (kept).
__global__ __launch_bounds__(512, 2) void pv_kernel(
    const u16* __restrict__ P, const u16* __restrict__ Vt,
    const float* __restrict__ rowsum, u16* __restrict__ Xn)
{
    __shared__ __align__(16) u16 As[2][128 * 64];   // 32 KB
    __shared__ __align__(16) u16 Bs[2][256 * 64];   // 64 KB

    const int swz = ((blockIdx.x & 7) << 5) + (blockIdx.x >> 3);
    const int b   = swz >> 6;
    const int bx  = (swz >> 2) & 15;
    const int by  = swz & 3;
    const int row0 = bx << 7, col0 = by << 8;

    const int tid = threadIdx.x;
    const int wid = tid >> 6, lane = tid & 63;
    const int l16 = lane & 15, g4 = lane >> 4;
    const int wr = wid >> 2, wc = wid & 3;

    const int sr   = tid >> 3;
    const int scol = ((tid & 7) ^ (sr & 7)) << 3;
    const u16* gA = P  + (size_t)(b * SS + row0 + sr) * SS + scol;
    const u16* gB = Vt + (size_t)(b * DD + col0 + sr) * SS + scol;
    char* const lA0 = (char*)As[0] + tid * 16;
    char* const lB0 = (char*)Bs[0] + tid * 16;
    char* const lA1 = (char*)As[1] + tid * 16;
    char* const lB1 = (char*)Bs[1] + tid * 16;

    const int aRow = (wr * 64 + l16) << 7;
    const int bRow = (wc * 64 + l16) << 7;
    const int cx0  = (g4 << 4) ^ ((l16 & 7) << 4);

    f32x4 acc[4][4];
    const f32x4 z4 = {0.f, 0.f, 0.f, 0.f};
#pragma unroll
    for (int i = 0; i < 4; ++i)
#pragma unroll
        for (int j = 0; j < 4; ++j) acc[i][j] = z4;

#define STAGE_PV(kt, la, lb) { \
    const u16* ga_ = gA + (kt) * 64; \
    const u16* gb_ = gB + (kt) * 64; \
    GLD16(ga_,            (la)); \
    GLD16(ga_ +  64 * SS, (la) + 8192); \
    GLD16(gb_,            (lb)); \
    GLD16(gb_ +  64 * SS, (lb) + 8192); \
    GLD16(gb_ + 128 * SS, (lb) + 16384); \
    GLD16(gb_ + 192 * SS, (lb) + 24576); }

#define LDA2(Ab_, mh, kx) { \
    const char* p_ = (const char*)(Ab_) + aRow + (mh) * 4096 + ((kx) ? (cx0 ^ 64) : cx0); \
    fa0 = *(const bf16x8*)(p_); \
    fa1 = *(const bf16x8*)(p_ + 2048); }

#define LDB4(Bb_, kx) { \
    const char* p_ = (const char*)(Bb_) + bRow + ((kx) ? (cx0 ^ 64) : cx0); \
    fb0 = *(const bf16x8*)(p_); \
    fb1 = *(const bf16x8*)(p_ + 2048); \
    fb2 = *(const bf16x8*)(p_ + 4096); \
    fb3 = *(const bf16x8*)(p_ + 6144); }

#define MROWP(mi, fa) \
    acc[mi][0] = __builtin_amdgcn_mfma_f32_16x16x32_bf16(fa, fb0, acc[mi][0],0,0,0); \
    acc[mi][1] = __builtin_amdgcn_mfma_f32_16x16x32_bf16(fa, fb1, acc[mi][1],0,0,0); \
    acc[mi][2] = __builtin_amdgcn_mfma_f32_16x16x32_bf16(fa, fb2, acc[mi][2],0,0,0); \
    acc[mi][3] = __builtin_amdgcn_mfma_f32_16x16x32_bf16(fa, fb3, acc[mi][3],0,0,0);

    STAGE_PV(0, lA0, lB0);
    STAGE_PV(1, lA1, lB1);
    asm volatile("s_waitcnt vmcnt(6)" ::: "memory");
    SCHED0(); __builtin_amdgcn_s_barrier(); SCHED0();

#pragma unroll 1
    for (int it = 0; it < 16; ++it){
        bf16x8 fa0, fa1, fb0, fb1, fb2, fb3;
        LDA2(As[0], 0, 0); LDB4(Bs[0], 0);
        PH_PRE(); MROWP(0,fa0) MROWP(1,fa1) PH_POST();
        LDA2(As[0], 1, 0);
        PH_PRE(); MROWP(2,fa0) MROWP(3,fa1) PH_POST();
        LDA2(As[0], 0, 1); LDB4(Bs[0], 1);
        PH_PRE(); MROWP(0,fa0) MROWP(1,fa1) PH_POST();
        LDA2(As[0], 1, 1);
        PH_PRE(); MROWP(2,fa0) MROWP(3,fa1) PH_POST();
        if (it < 15){
            STAGE_PV(2*it+2, lA0, lB0);
            asm volatile("s_waitcnt vmcnt(6)" ::: "memory");
        } else {
            asm volatile("s_waitcnt vmcnt(0)" ::: "memory");
        }
        SCHED0(); __builtin_amdgcn_s_barrier(); SCHED0();
        LDA2(As[1], 0, 0); LDB4(Bs[1], 0);
        PH_PRE(); MROWP(0,fa0) MROWP(1,fa1) PH_POST();
        LDA2(As[1], 1, 0);
        PH_PRE(); MROWP(2,fa0) MROWP(3,fa1) PH_POST();
        LDA2(As[1], 0, 1); LDB4(Bs[1], 1);
        PH_PRE(); MROWP(0,fa0) MROWP(1,fa1) PH_POST();
        LDA2(As[1], 1, 1);
        PH_PRE(); MROWP(2,fa0) MROWP(3,fa1) PH_POST();
        if (it < 15){
            STAGE_PV(2*it+3, lA1, lB1);
            asm volatile("s_waitcnt vmcnt(6)" ::: "memory");
            SCHED0(); __builtin_amdgcn_s_barrier(); SCHED0();
        }
    }
#undef STAGE_PV
#undef LDA2
#undef LDB4
#undef MROWP

#pragma unroll
    for (int m = 0; m < 4; ++m){
        float inv[4];
#pragma unroll
        for (int r = 0; r < 4; ++r)
            inv[r] = 1.f / rowsum[b * SS + row0 + wr * 64 + m * 16 + g4 * 4 + r];
#pragma unroll
        for (int n = 0; n < 4; ++n){
            const int gcol = col0 + wc * 64 + n * 16 + l16;
#pragma unroll
            for (int r = 0; r < 4; ++r){
                const int grow = row0 + wr * 64 + m * 16 + g4 * 4 + r;
                Xn[(size_t)(b * SS + grow) * DD + gcol] = f2bf(acc[m][n][r] * inv[r]);
            }
        }
    }
}

// ---------------- pass 3: LayerNorm over d ----------------
__global__ __launch_bounds__(256) void ln_kernel(
    const u16* __restrict__ Xn, const float* __restrict__ gamma,
    const float* __restrict__ beta, float* __restrict__ out)
{
    __shared__ float red[2][4];
    const int row = blockIdx.x;      // b*S + s
    const int t = threadIdx.x;
    short4v xv = *(const short4v*)&Xn[(size_t)row * DD + t * 4];
    float x[4];
#pragma unroll
    for (int j = 0; j < 4; ++j)
        x[j] = __uint_as_float(((unsigned)(u16)xv[j]) << 16);
    float s  = x[0] + x[1] + x[2] + x[3];
    float sq = x[0]*x[0] + x[1]*x[1] + x[2]*x[2] + x[3]*x[3];
#pragma unroll
    for (int d = 1; d < 64; d <<= 1){ s += __shfl_xor(s, d); sq += __shfl_xor(sq, d); }
    const int wv = t >> 6;
    if ((t & 63) == 0){ red[0][wv] = s; red[1][wv] = sq; }
    __syncthreads();
    float S  = red[0][0] + red[0][1] + red[0][2] + red[0][3];
    float Sq = red[1][0] + red[1][1] + red[1][2] + red[1][3];
    float mu = S * (1.f / 1024.f);
    float var = Sq * (1.f / 1024.f) - mu * mu;
    float rstd = rsqrtf(var + 1e-5f);
    float4v g  = *(const float4v*)&gamma[t * 4];
    float4v be = *(const float4v*)&beta[t * 4];
    float4v o;
#pragma unroll
    for (int j = 0; j < 4; ++j) o[j] = (x[j] - mu) * rstd * g[j] + be[j];
    *(float4v*)&out[(size_t)row * DD + t * 4] = o;
}

extern "C" void kernel_launch(void* const* d_in, const int* in_sizes, int n_in,
                              void* d_out, int out_size, void* d_ws, size_t ws_size,
                              hipStream_t stream) {
    const float* q     = (const float*)d_in[0];
    const float* k     = (const float*)d_in[1];
    const float* v     = (const float*)d_in[2];
    const int*   mask  = (const int*)d_in[3];
    const float* gamma = (const float*)d_in[4];
    const float* beta  = (const float*)d_in[5];
    float* out = (float*)d_out;

    u16* Qb = (u16*)d_ws;                                  // 16 MB (pre-scaled by 1/sqrt(d))
    u16* Kb = Qb + (size_t)BB * SS * DD;                   // 16 MB
    u16* Vt = Kb + (size_t)BB * SS * DD;                   // 16 MB
    u16* P  = Vt + (size_t)BB * SS * DD;                   // 32 MB
    u16* Xn = P  + (size_t)BB * SS * SS;                   // 16 MB
    float* rowsum = (float*)(Xn + (size_t)BB * SS * DD);   // 32 KB
    // bitmask (2 MB) aliases the Xn region: written by prep, consumed by qk,
    // then Xn is overwritten by pv (strictly after qk on the same stream).
    unsigned int* mbits = (unsigned int*)Xn;

    prep_kernel<<<8224, 256, 0, stream>>>(q, k, v, mask, Qb, Kb, Vt, mbits, rowsum);
    qk_kernel<<<256, 512, 0, stream>>>(Qb, Kb, (const u64*)mbits, P, rowsum);
    pv_kernel<<<256, 512, 0, stream>>>(P, Vt, rowsum, Xn);
    ln_kernel<<<BB * SS, 256, 0, stream>>>(Xn, gamma, beta, out);
}